// Round 1
// baseline (770.793 us; speedup 1.0000x reference)
//
#include <hip/hip_runtime.h>

// DCGRU cell, MI355X. Structure:
//   All diffusion intermediates stored TRANSPOSED: XT[col = f*64+b][node n] in bf16,
//   so the Chebyshev GEMM C[n_node][col] = sum_k S[n][k] * XT[col][k] is an NT GEMM
//   with K-contiguous operands on both sides -> ds_read_b128 fragments.
//   cheb_gemm: 128x128 tile, BK=32, mfma_f32_16x16x32_bf16, global_load_lds width=16.
//   proj kernels: stage 330x64 bf16 activation slice in LDS, fp32 MAC with broadcast
//   float4 weight loads; epilogues fuse sigmoid / (r*hx -> X0'^T) / tanh / GRU blend.
//   d_out doubles as u-buffer (identical index layout (b*1024+n)*64+o).

typedef unsigned short u16;
typedef unsigned int u32;
typedef short s16x8 __attribute__((ext_vector_type(8)));
typedef float f32x4 __attribute__((ext_vector_type(4)));
typedef u16 u16x4 __attribute__((ext_vector_type(4)));

#define NN 1024
#define NB 64
#define NF 66
#define NCOLS 4224  // NF*NB

__device__ __forceinline__ u16 f2bf(float f) {
  u32 u = __builtin_bit_cast(u32, f);
  u = (u + 0x7fffu + ((u >> 16) & 1u)) >> 16;  // RNE
  return (u16)u;
}
__device__ __forceinline__ float bf2f(u16 h) {
  u32 u = ((u32)h) << 16;
  return __builtin_bit_cast(float, u);
}

__device__ __forceinline__ void gload16(const void* g, void* l) {
  __builtin_amdgcn_global_load_lds(
      (const __attribute__((address_space(1))) u32*)g,
      (__attribute__((address_space(3))) u32*)l, 16, 0, 0);
}

// ---------------- pack kernels ----------------

__global__ __launch_bounds__(256) void pack_supports(
    const float* __restrict__ s0, const float* __restrict__ s1,
    u16* __restrict__ d0, u16* __restrict__ d1) {
  int i = (blockIdx.x * 256 + threadIdx.x) * 4;
  f32x4 a = *(const f32x4*)(s0 + i);
  f32x4 b = *(const f32x4*)(s1 + i);
  u16x4 oa, ob;
  oa.x = f2bf(a.x); oa.y = f2bf(a.y); oa.z = f2bf(a.z); oa.w = f2bf(a.w);
  ob.x = f2bf(b.x); ob.y = f2bf(b.y); ob.z = f2bf(b.z); ob.w = f2bf(b.w);
  *(u16x4*)(d0 + i) = oa;
  *(u16x4*)(d1 + i) = ob;
}

// rows f=0,1 of X0^T and X0'^T: X0T[f*64+b][n] = inputs[b][2n+f]
__global__ __launch_bounds__(256) void pack_x0_inputs(
    const float* __restrict__ inp, u16* __restrict__ x0t, u16* __restrict__ x0pt) {
  int b = blockIdx.x, t = threadIdx.x;
  int n4 = t * 4;
  const float* src = inp + b * 2048 + n4 * 2;
  f32x4 a = *(const f32x4*)src;
  f32x4 c = *(const f32x4*)(src + 4);
  u16x4 r0, r1;
  r0.x = f2bf(a.x); r0.y = f2bf(a.z); r0.z = f2bf(c.x); r0.w = f2bf(c.z);  // f=0
  r1.x = f2bf(a.y); r1.y = f2bf(a.w); r1.z = f2bf(c.y); r1.w = f2bf(c.w);  // f=1
  size_t o0 = (size_t)(b)*NN + n4;
  size_t o1 = (size_t)(64 + b) * NN + n4;
  *(u16x4*)(x0t + o0) = r0;  *(u16x4*)(x0t + o1) = r1;
  *(u16x4*)(x0pt + o0) = r0; *(u16x4*)(x0pt + o1) = r1;
}

// rows f>=2 of X0^T: X0T[(2+u)*64+b][n] = hx[b][n*64+u]  (64x64 LDS transpose tiles)
__global__ __launch_bounds__(256) void pack_x0_hx(
    const float* __restrict__ hx, u16* __restrict__ x0t) {
  __shared__ float tile[64][65];
  int n0 = blockIdx.x * 64, b = blockIdx.y, t = threadIdx.x;
  int u4 = (t & 15) * 4, r0 = t >> 4;
#pragma unroll
  for (int p = 0; p < 4; p++) {
    int row = p * 16 + r0;
    f32x4 v = *(const f32x4*)(hx + ((size_t)b << 16) + (size_t)(n0 + row) * 64 + u4);
    tile[row][u4] = v.x; tile[row][u4 + 1] = v.y;
    tile[row][u4 + 2] = v.z; tile[row][u4 + 3] = v.w;
  }
  __syncthreads();
  int n4 = (t & 15) * 4, uu0 = t >> 4;
#pragma unroll
  for (int p = 0; p < 4; p++) {
    int u = p * 16 + uu0;
    u16x4 o;
    o.x = f2bf(tile[n4][u]);     o.y = f2bf(tile[n4 + 1][u]);
    o.z = f2bf(tile[n4 + 2][u]); o.w = f2bf(tile[n4 + 3][u]);
    *(u16x4*)&x0t[(size_t)((2 + u) * 64 + b) * NN + n0 + n4] = o;
  }
}

// ---------------- Chebyshev GEMM ----------------
// C[node][col] = S_z[node][:] . XT_z[col][:],  write Xo_z[col][node] (bf16),
// optional fused epilogue: 2*C - Xprev.
__global__ __launch_bounds__(256) void cheb_gemm(
    const u16* __restrict__ S0, const u16* __restrict__ S1,
    const u16* __restrict__ Xi0, const u16* __restrict__ Xi1,
    u16* __restrict__ Xo0, u16* __restrict__ Xo1,
    const u16* __restrict__ Xprev, int use_prev) {
  __shared__ u16 As[128 * 32];
  __shared__ u16 Bs[128 * 32];
  const int t = threadIdx.x;
  const int lane = t & 63;
  const int w = t >> 6;
  const int n0 = blockIdx.x * 128;  // col tile (XT row)
  const int m0 = blockIdx.y * 128;  // node tile
  const u16* S = blockIdx.z ? S1 : S0;
  const u16* Xi = blockIdx.z ? Xi1 : Xi0;
  u16* Xo = blockIdx.z ? Xo1 : Xo0;

  const int lrow = lane >> 2;
  const int lkof = (lane & 3) * 8;
  const u16* ga0 = S + (size_t)(m0 + w * 32 + lrow) * NN + lkof;
  const u16* ga1 = ga0 + (size_t)16 * NN;
  const u16* gb0 = Xi + (size_t)(n0 + w * 32 + lrow) * NN + lkof;
  const u16* gb1 = gb0 + (size_t)16 * NN;
  u16* lA0 = &As[(w * 32) * 32];
  u16* lA1 = &As[(w * 32 + 16) * 32];
  u16* lB0 = &Bs[(w * 32) * 32];
  u16* lB1 = &Bs[(w * 32 + 16) * 32];

  const int wm = (w >> 1) * 64;
  const int wn = (w & 1) * 64;
  const int fr = lane & 15;
  const int fko = (lane >> 4) * 8;

  f32x4 acc[4][4];
#pragma unroll
  for (int i = 0; i < 4; i++)
#pragma unroll
    for (int j = 0; j < 4; j++) acc[i][j] = f32x4{0.f, 0.f, 0.f, 0.f};

  for (int k0 = 0; k0 < 1024; k0 += 32) {
    __syncthreads();
    gload16(ga0, lA0);
    gload16(ga1, lA1);
    gload16(gb0, lB0);
    gload16(gb1, lB1);
    __syncthreads();
    s16x8 af[4], bfr[4];
#pragma unroll
    for (int i = 0; i < 4; i++)
      af[i] = *(const s16x8*)&As[(wm + i * 16 + fr) * 32 + fko];
#pragma unroll
    for (int i = 0; i < 4; i++)
      bfr[i] = *(const s16x8*)&Bs[(wn + i * 16 + fr) * 32 + fko];
#pragma unroll
    for (int i = 0; i < 4; i++)
#pragma unroll
      for (int j = 0; j < 4; j++)
        acc[i][j] = __builtin_amdgcn_mfma_f32_16x16x32_bf16(af[i], bfr[j], acc[i][j], 0, 0, 0);
    ga0 += 32; ga1 += 32; gb0 += 32; gb1 += 32;
  }

  // C/D layout: col = lane&15, row = (lane>>4)*4 + reg
  const int nr0 = (lane >> 4) << 2;
#pragma unroll
  for (int i = 0; i < 4; i++) {
    const int node = m0 + wm + i * 16 + nr0;
#pragma unroll
    for (int j = 0; j < 4; j++) {
      const int colg = n0 + wn + j * 16 + fr;
      size_t off = (size_t)colg * NN + node;
      f32x4 c = acc[i][j];
      if (use_prev) {
        u16x4 p = *(const u16x4*)&Xprev[off];
        c.x = 2.f * c.x - bf2f(p.x);
        c.y = 2.f * c.y - bf2f(p.y);
        c.z = 2.f * c.z - bf2f(p.z);
        c.w = 2.f * c.w - bf2f(p.w);
      }
      u16x4 o;
      o.x = f2bf(c.x); o.y = f2bf(c.y); o.z = f2bf(c.z); o.w = f2bf(c.w);
      *(u16x4*)&Xo[off] = o;
    }
  }
}

// ---------------- projections ----------------

__device__ __forceinline__ void stage_x(u16* A, const u16* __restrict__ X, int mm,
                                        int b, int n0, int t) {
  for (int idx = t; idx < 66 * 32; idx += 256) {
    int f = idx >> 5, pos = (idx & 31) * 2;
    *(u32*)&A[(mm * 66 + f) * 64 + pos] =
        *(const u32*)(X + (size_t)(f * 64 + b) * NN + n0 + pos);
  }
}

// gconv1 projection: sigmoid epilogue; r*hx -> X0'^T rows f>=2; u -> uout (=d_out).
__global__ __launch_bounds__(256) void proj1(
    const u16* __restrict__ X0, const u16* __restrict__ X1, const u16* __restrict__ X2,
    const u16* __restrict__ X3, const u16* __restrict__ X4,
    const float* __restrict__ W, const float* __restrict__ bias,
    const float* __restrict__ hx, u16* __restrict__ X0p, float* __restrict__ uout) {
  __shared__ u16 A[330 * 64];
  const int t = threadIdx.x;
  const int n0 = blockIdx.x * 64;
  const int b = blockIdx.y;
  stage_x(A, X0, 0, b, n0, t);
  stage_x(A, X1, 1, b, n0, t);
  stage_x(A, X2, 2, b, n0, t);
  stage_x(A, X3, 3, b, n0, t);
  stage_x(A, X4, 4, b, n0, t);
  __syncthreads();

  const int n = t & 63;
  const int ob = (t >> 6) * 32;
  float acc[32];
#pragma unroll
  for (int j = 0; j < 32; j++) acc[j] = 0.f;

  for (int m = 0; m < 5; m++) {
    const u16* Ap = &A[m * 66 * 64 + n];
    const float* Wp = W + m * 128 + ob;  // row index f*5+m, row len 128
    for (int f = 0; f < 66; f++) {
      float a = bf2f(Ap[f * 64]);
      const f32x4* wv = (const f32x4*)(Wp + f * 5 * 128);
#pragma unroll
      for (int j = 0; j < 8; j++) {
        f32x4 wq = wv[j];
        acc[j * 4 + 0] += a * wq.x; acc[j * 4 + 1] += a * wq.y;
        acc[j * 4 + 2] += a * wq.z; acc[j * 4 + 3] += a * wq.w;
      }
    }
  }

  if (ob < 64) {  // r part -> X0'^T
    const float* hxp = hx + ((size_t)b << 16) + (size_t)(n0 + n) * 64 + ob;
    u16* xp = X0p + (size_t)((2 + ob) * 64 + b) * NN + n0 + n;
#pragma unroll
    for (int j4 = 0; j4 < 32; j4 += 4) {
      f32x4 hv = *(const f32x4*)(hxp + j4);
      float v0 = 1.f / (1.f + __expf(-(acc[j4 + 0] + bias[ob + j4 + 0])));
      float v1 = 1.f / (1.f + __expf(-(acc[j4 + 1] + bias[ob + j4 + 1])));
      float v2 = 1.f / (1.f + __expf(-(acc[j4 + 2] + bias[ob + j4 + 2])));
      float v3 = 1.f / (1.f + __expf(-(acc[j4 + 3] + bias[ob + j4 + 3])));
      xp[(size_t)(j4 + 0) * 64 * NN] = f2bf(v0 * hv.x);
      xp[(size_t)(j4 + 1) * 64 * NN] = f2bf(v1 * hv.y);
      xp[(size_t)(j4 + 2) * 64 * NN] = f2bf(v2 * hv.z);
      xp[(size_t)(j4 + 3) * 64 * NN] = f2bf(v3 * hv.w);
    }
  } else {  // u part -> uout (d_out scratch)
    float* up = uout + (((size_t)b << 10) + (n0 + n)) * 64 + (ob - 64);
#pragma unroll
    for (int j4 = 0; j4 < 32; j4 += 4) {
      f32x4 v;
      v.x = 1.f / (1.f + __expf(-(acc[j4 + 0] + bias[ob + j4 + 0])));
      v.y = 1.f / (1.f + __expf(-(acc[j4 + 1] + bias[ob + j4 + 1])));
      v.z = 1.f / (1.f + __expf(-(acc[j4 + 2] + bias[ob + j4 + 2])));
      v.w = 1.f / (1.f + __expf(-(acc[j4 + 3] + bias[ob + j4 + 3])));
      *(f32x4*)(up + j4) = v;
    }
  }
}

// gconv2 projection: tanh + GRU blend. uin aliases out (same index layout) - no restrict.
__global__ __launch_bounds__(256) void proj2(
    const u16* __restrict__ X0, const u16* __restrict__ X1, const u16* __restrict__ X2,
    const u16* __restrict__ X3, const u16* __restrict__ X4,
    const float* __restrict__ W, const float* __restrict__ bias,
    const float* __restrict__ hx, const float* uin, float* out) {
  __shared__ u16 A[330 * 64];
  const int t = threadIdx.x;
  const int n0 = blockIdx.x * 64;
  const int b = blockIdx.y;
  stage_x(A, X0, 0, b, n0, t);
  stage_x(A, X1, 1, b, n0, t);
  stage_x(A, X2, 2, b, n0, t);
  stage_x(A, X3, 3, b, n0, t);
  stage_x(A, X4, 4, b, n0, t);
  __syncthreads();

  const int n = t & 63;
  const int ob = (t >> 6) * 16;
  float acc[16];
#pragma unroll
  for (int j = 0; j < 16; j++) acc[j] = 0.f;

  for (int m = 0; m < 5; m++) {
    const u16* Ap = &A[m * 66 * 64 + n];
    const float* Wp = W + m * 64 + ob;  // row index f*5+m, row len 64
    for (int f = 0; f < 66; f++) {
      float a = bf2f(Ap[f * 64]);
      const f32x4* wv = (const f32x4*)(Wp + f * 5 * 64);
#pragma unroll
      for (int j = 0; j < 4; j++) {
        f32x4 wq = wv[j];
        acc[j * 4 + 0] += a * wq.x; acc[j * 4 + 1] += a * wq.y;
        acc[j * 4 + 2] += a * wq.z; acc[j * 4 + 3] += a * wq.w;
      }
    }
  }

  const size_t base = (((size_t)b << 10) + (n0 + n)) * 64 + ob;
#pragma unroll
  for (int j4 = 0; j4 < 16; j4 += 4) {
    f32x4 uu = *(const f32x4*)(uin + base + j4);
    f32x4 hh = *(const f32x4*)(hx + base + j4);
    f32x4 r;
    float c0 = tanhf(acc[j4 + 0] + bias[ob + j4 + 0]);
    float c1 = tanhf(acc[j4 + 1] + bias[ob + j4 + 1]);
    float c2 = tanhf(acc[j4 + 2] + bias[ob + j4 + 2]);
    float c3 = tanhf(acc[j4 + 3] + bias[ob + j4 + 3]);
    r.x = uu.x * hh.x + (1.f - uu.x) * c0;
    r.y = uu.y * hh.y + (1.f - uu.y) * c1;
    r.z = uu.z * hh.z + (1.f - uu.z) * c2;
    r.w = uu.w * hh.w + (1.f - uu.w) * c3;
    *(f32x4*)(out + base + j4) = r;
  }
}

// ---------------- launch ----------------

extern "C" void kernel_launch(void* const* d_in, const int* in_sizes, int n_in,
                              void* d_out, int out_size, void* d_ws, size_t ws_size,
                              hipStream_t stream) {
  (void)in_sizes; (void)n_in; (void)out_size; (void)ws_size;
  const float* inp = (const float*)d_in[0];
  const float* hx  = (const float*)d_in[1];
  const float* s0  = (const float*)d_in[2];
  const float* s1  = (const float*)d_in[3];
  const float* Wo  = (const float*)d_in[4];
  const float* bo  = (const float*)d_in[5];
  const float* Wu  = (const float*)d_in[6];
  const float* bu  = (const float*)d_in[7];
  float* out = (float*)d_out;

  char* p = (char*)d_ws;
  u16* Sb0 = (u16*)p; p += (size_t)NN * NN * 2;
  u16* Sb1 = (u16*)p; p += (size_t)NN * NN * 2;
  const size_t xbytes = (size_t)NCOLS * NN * 2;
  u16* X0T = (u16*)p; p += xbytes;
  u16* X1T = (u16*)p; p += xbytes;
  u16* X2T = (u16*)p; p += xbytes;
  u16* X3T = (u16*)p; p += xbytes;
  u16* X4T = (u16*)p; p += xbytes;
  u16* X0P = (u16*)p; p += xbytes;
  // total ws use: 4 MB + 6*8.25 MB = 53.5 MB

  pack_supports<<<dim3(1024), dim3(256), 0, stream>>>(s0, s1, Sb0, Sb1);
  pack_x0_inputs<<<dim3(64), dim3(256), 0, stream>>>(inp, X0T, X0P);
  pack_x0_hx<<<dim3(16, 64), dim3(256), 0, stream>>>(hx, X0T);
  // gconv1 Chebyshev: X1=S0 X0, X3=S1 X0 ; X2=2 S0 X1 - X0, X4=2 S1 X3 - X0
  cheb_gemm<<<dim3(33, 8, 2), dim3(256), 0, stream>>>(Sb0, Sb1, X0T, X0T, X1T, X3T,
                                                      (const u16*)nullptr, 0);
  cheb_gemm<<<dim3(33, 8, 2), dim3(256), 0, stream>>>(Sb0, Sb1, X1T, X3T, X2T, X4T, X0T, 1);
  proj1<<<dim3(16, 64), dim3(256), 0, stream>>>(X0T, X1T, X2T, X3T, X4T, Wo, bo, hx, X0P, out);
  // gconv2 Chebyshev on X0' (reuse X1..X4 buffers)
  cheb_gemm<<<dim3(33, 8, 2), dim3(256), 0, stream>>>(Sb0, Sb1, X0P, X0P, X1T, X3T,
                                                      (const u16*)nullptr, 0);
  cheb_gemm<<<dim3(33, 8, 2), dim3(256), 0, stream>>>(Sb0, Sb1, X1T, X3T, X2T, X4T, X0P, 1);
  proj2<<<dim3(16, 64), dim3(256), 0, stream>>>(X0P, X1T, X2T, X3T, X4T, Wu, bu, hx, out, out);
}

// Round 2
// 398.691 us; speedup vs baseline: 1.9333x; 1.9333x over previous
//
#include <hip/hip_runtime.h>

// DCGRU cell, MI355X. Structure:
//   All diffusion intermediates stored TRANSPOSED: XT[col = f*64+b][node n] in bf16.
//   cheb_gemm: 128x128 tile, BK=32, mfma_f32_16x16x32_bf16, global_load_lds width=16.
//   proj1/proj2 (round 2): MFMA GEMM [64n x 330k] @ [330k x {128,64}o] per (n-block,b).
//     W packed once to bf16 as Wt[o][kp], kp=m*66+f, K padded to 352.
//     A staged in LDS [kp][n] stride 66 (conflict-free strided A-frag reads),
//     B-frags read straight from global Wt (L1/L2-hot, shared by all blocks).
//   d_out doubles as u-buffer (identical index layout (b*1024+n)*64+o).

typedef unsigned short u16;
typedef unsigned int u32;
typedef short s16x8 __attribute__((ext_vector_type(8)));
typedef float f32x4 __attribute__((ext_vector_type(4)));
typedef u16 u16x4 __attribute__((ext_vector_type(4)));

#define NN 1024
#define NB 64
#define NF 66
#define NCOLS 4224  // NF*NB
#define KPAD 352    // 330 padded to 11*32

__device__ __forceinline__ u16 f2bf(float f) {
  u32 u = __builtin_bit_cast(u32, f);
  u = (u + 0x7fffu + ((u >> 16) & 1u)) >> 16;  // RNE
  return (u16)u;
}
__device__ __forceinline__ float bf2f(u16 h) {
  u32 u = ((u32)h) << 16;
  return __builtin_bit_cast(float, u);
}

__device__ __forceinline__ void gload16(const void* g, void* l) {
  __builtin_amdgcn_global_load_lds(
      (const __attribute__((address_space(1))) u32*)g,
      (__attribute__((address_space(3))) u32*)l, 16, 0, 0);
}

// ---------------- pack kernels ----------------

__global__ __launch_bounds__(256) void pack_supports(
    const float* __restrict__ s0, const float* __restrict__ s1,
    u16* __restrict__ d0, u16* __restrict__ d1) {
  int i = (blockIdx.x * 256 + threadIdx.x) * 4;
  f32x4 a = *(const f32x4*)(s0 + i);
  f32x4 b = *(const f32x4*)(s1 + i);
  u16x4 oa, ob;
  oa.x = f2bf(a.x); oa.y = f2bf(a.y); oa.z = f2bf(a.z); oa.w = f2bf(a.w);
  ob.x = f2bf(b.x); ob.y = f2bf(b.y); ob.z = f2bf(b.z); ob.w = f2bf(b.w);
  *(u16x4*)(d0 + i) = oa;
  *(u16x4*)(d1 + i) = ob;
}

// Wt[o][kp] = W[f*5+m][o], kp = m*66+f, zero-padded kp in [330,352)
__global__ __launch_bounds__(64) void pack_w(
    const float* __restrict__ W, u16* __restrict__ Wt, int ldo) {
  int o = blockIdx.y;
  int kp = blockIdx.x * 64 + threadIdx.x;
  if (kp >= KPAD) return;
  float v = 0.f;
  if (kp < 330) {
    int m = kp / 66;
    int f = kp - m * 66;
    v = W[(f * 5 + m) * ldo + o];
  }
  Wt[(size_t)o * KPAD + kp] = f2bf(v);
}

// rows f=0,1 of X0^T and X0'^T: X0T[f*64+b][n] = inputs[b][2n+f]
__global__ __launch_bounds__(256) void pack_x0_inputs(
    const float* __restrict__ inp, u16* __restrict__ x0t, u16* __restrict__ x0pt) {
  int b = blockIdx.x, t = threadIdx.x;
  int n4 = t * 4;
  const float* src = inp + b * 2048 + n4 * 2;
  f32x4 a = *(const f32x4*)src;
  f32x4 c = *(const f32x4*)(src + 4);
  u16x4 r0, r1;
  r0.x = f2bf(a.x); r0.y = f2bf(a.z); r0.z = f2bf(c.x); r0.w = f2bf(c.z);  // f=0
  r1.x = f2bf(a.y); r1.y = f2bf(a.w); r1.z = f2bf(c.y); r1.w = f2bf(c.w);  // f=1
  size_t o0 = (size_t)(b)*NN + n4;
  size_t o1 = (size_t)(64 + b) * NN + n4;
  *(u16x4*)(x0t + o0) = r0;  *(u16x4*)(x0t + o1) = r1;
  *(u16x4*)(x0pt + o0) = r0; *(u16x4*)(x0pt + o1) = r1;
}

// rows f>=2 of X0^T: X0T[(2+u)*64+b][n] = hx[b][n*64+u]  (64x64 LDS transpose tiles)
__global__ __launch_bounds__(256) void pack_x0_hx(
    const float* __restrict__ hx, u16* __restrict__ x0t) {
  __shared__ float tile[64][65];
  int n0 = blockIdx.x * 64, b = blockIdx.y, t = threadIdx.x;
  int u4 = (t & 15) * 4, r0 = t >> 4;
#pragma unroll
  for (int p = 0; p < 4; p++) {
    int row = p * 16 + r0;
    f32x4 v = *(const f32x4*)(hx + ((size_t)b << 16) + (size_t)(n0 + row) * 64 + u4);
    tile[row][u4] = v.x; tile[row][u4 + 1] = v.y;
    tile[row][u4 + 2] = v.z; tile[row][u4 + 3] = v.w;
  }
  __syncthreads();
  int n4 = (t & 15) * 4, uu0 = t >> 4;
#pragma unroll
  for (int p = 0; p < 4; p++) {
    int u = p * 16 + uu0;
    u16x4 o;
    o.x = f2bf(tile[n4][u]);     o.y = f2bf(tile[n4 + 1][u]);
    o.z = f2bf(tile[n4 + 2][u]); o.w = f2bf(tile[n4 + 3][u]);
    *(u16x4*)&x0t[(size_t)((2 + u) * 64 + b) * NN + n0 + n4] = o;
  }
}

// ---------------- Chebyshev GEMM ----------------
// C[node][col] = S_z[node][:] . XT_z[col][:],  write Xo_z[col][node] (bf16),
// optional fused epilogue: 2*C - Xprev.
__global__ __launch_bounds__(256) void cheb_gemm(
    const u16* __restrict__ S0, const u16* __restrict__ S1,
    const u16* __restrict__ Xi0, const u16* __restrict__ Xi1,
    u16* __restrict__ Xo0, u16* __restrict__ Xo1,
    const u16* __restrict__ Xprev, int use_prev) {
  __shared__ u16 As[128 * 32];
  __shared__ u16 Bs[128 * 32];
  const int t = threadIdx.x;
  const int lane = t & 63;
  const int w = t >> 6;
  const int n0 = blockIdx.x * 128;  // col tile (XT row)
  const int m0 = blockIdx.y * 128;  // node tile
  const u16* S = blockIdx.z ? S1 : S0;
  const u16* Xi = blockIdx.z ? Xi1 : Xi0;
  u16* Xo = blockIdx.z ? Xo1 : Xo0;

  const int lrow = lane >> 2;
  const int lkof = (lane & 3) * 8;
  const u16* ga0 = S + (size_t)(m0 + w * 32 + lrow) * NN + lkof;
  const u16* ga1 = ga0 + (size_t)16 * NN;
  const u16* gb0 = Xi + (size_t)(n0 + w * 32 + lrow) * NN + lkof;
  const u16* gb1 = gb0 + (size_t)16 * NN;
  u16* lA0 = &As[(w * 32) * 32];
  u16* lA1 = &As[(w * 32 + 16) * 32];
  u16* lB0 = &Bs[(w * 32) * 32];
  u16* lB1 = &Bs[(w * 32 + 16) * 32];

  const int wm = (w >> 1) * 64;
  const int wn = (w & 1) * 64;
  const int fr = lane & 15;
  const int fko = (lane >> 4) * 8;

  f32x4 acc[4][4];
#pragma unroll
  for (int i = 0; i < 4; i++)
#pragma unroll
    for (int j = 0; j < 4; j++) acc[i][j] = f32x4{0.f, 0.f, 0.f, 0.f};

  for (int k0 = 0; k0 < 1024; k0 += 32) {
    __syncthreads();
    gload16(ga0, lA0);
    gload16(ga1, lA1);
    gload16(gb0, lB0);
    gload16(gb1, lB1);
    __syncthreads();
    s16x8 af[4], bfr[4];
#pragma unroll
    for (int i = 0; i < 4; i++)
      af[i] = *(const s16x8*)&As[(wm + i * 16 + fr) * 32 + fko];
#pragma unroll
    for (int i = 0; i < 4; i++)
      bfr[i] = *(const s16x8*)&Bs[(wn + i * 16 + fr) * 32 + fko];
#pragma unroll
    for (int i = 0; i < 4; i++)
#pragma unroll
      for (int j = 0; j < 4; j++)
        acc[i][j] = __builtin_amdgcn_mfma_f32_16x16x32_bf16(af[i], bfr[j], acc[i][j], 0, 0, 0);
    ga0 += 32; ga1 += 32; gb0 += 32; gb1 += 32;
  }

  // C/D layout: col = lane&15, row = (lane>>4)*4 + reg
  const int nr0 = (lane >> 4) << 2;
#pragma unroll
  for (int i = 0; i < 4; i++) {
    const int node = m0 + wm + i * 16 + nr0;
#pragma unroll
    for (int j = 0; j < 4; j++) {
      const int colg = n0 + wn + j * 16 + fr;
      size_t off = (size_t)colg * NN + node;
      f32x4 c = acc[i][j];
      if (use_prev) {
        u16x4 p = *(const u16x4*)&Xprev[off];
        c.x = 2.f * c.x - bf2f(p.x);
        c.y = 2.f * c.y - bf2f(p.y);
        c.z = 2.f * c.z - bf2f(p.z);
        c.w = 2.f * c.w - bf2f(p.w);
      }
      u16x4 o;
      o.x = f2bf(c.x); o.y = f2bf(c.y); o.z = f2bf(c.z); o.w = f2bf(c.w);
      *(u16x4*)&Xo[off] = o;
    }
  }
}

// ---------------- projections (MFMA) ----------------

// stage activation slice into LDS A[kp][n], row stride 66, kp = mm*66+f
__device__ __forceinline__ void stage_x(u16* A, const u16* __restrict__ X, int mm,
                                        int b, int n0, int t) {
  for (int idx = t; idx < 66 * 32; idx += 256) {
    int f = idx >> 5, pos = (idx & 31) * 2;
    *(u32*)&A[(mm * 66 + f) * 66 + pos] =
        *(const u32*)(X + (size_t)(f * 64 + b) * NN + n0 + pos);
  }
}

__device__ __forceinline__ void zero_pad_rows(u16* A, int t) {
  u32* A32 = (u32*)A;
  for (int idx = t; idx < (KPAD - 330) * 33; idx += 256) A32[330 * 33 + idx] = 0;
}

// gconv1 projection: [64n x 330] @ Wt1^T -> 128 outs; sigmoid; r*hx -> X0'^T; u -> uout.
__global__ __launch_bounds__(256) void proj1(
    const u16* __restrict__ X0, const u16* __restrict__ X1, const u16* __restrict__ X2,
    const u16* __restrict__ X3, const u16* __restrict__ X4,
    const u16* __restrict__ Wt, const float* __restrict__ bias,
    const float* __restrict__ hx, u16* __restrict__ X0p, float* __restrict__ uout) {
  __shared__ u16 A[KPAD * 66];
  const int t = threadIdx.x;
  const int n0 = blockIdx.x * 64;
  const int b = blockIdx.y;
  stage_x(A, X0, 0, b, n0, t);
  stage_x(A, X1, 1, b, n0, t);
  stage_x(A, X2, 2, b, n0, t);
  stage_x(A, X3, 3, b, n0, t);
  stage_x(A, X4, 4, b, n0, t);
  zero_pad_rows(A, t);
  __syncthreads();

  const int lane = t & 63;
  const int w = t >> 6;
  const int fr = lane & 15;
  const int ko8 = (lane >> 4) * 8;

  f32x4 acc[8];
#pragma unroll
  for (int j = 0; j < 8; j++) acc[j] = f32x4{0.f, 0.f, 0.f, 0.f};

  for (int kc = 0; kc < KPAD; kc += 32) {
    s16x8 af;
#pragma unroll
    for (int j = 0; j < 8; j++)
      af[j] = (short)A[(kc + ko8 + j) * 66 + w * 16 + fr];
#pragma unroll
    for (int j = 0; j < 8; j++) {
      s16x8 bf = *(const s16x8*)&Wt[(size_t)(j * 16 + fr) * KPAD + kc + ko8];
      acc[j] = __builtin_amdgcn_mfma_f32_16x16x32_bf16(af, bf, acc[j], 0, 0, 0);
    }
  }

  // D layout: col(o within sub) = lane&15, row(n within sub) = (lane>>4)*4 + reg
  const int nl0 = (lane >> 4) * 4;
  const int n = n0 + w * 16 + nl0;  // + reg
#pragma unroll
  for (int j = 0; j < 8; j++) {
    const int o = j * 16 + fr;
    const float bs = bias[o];
    f32x4 v;
    v.x = 1.f / (1.f + __expf(-(acc[j].x + bs)));
    v.y = 1.f / (1.f + __expf(-(acc[j].y + bs)));
    v.z = 1.f / (1.f + __expf(-(acc[j].z + bs)));
    v.w = 1.f / (1.f + __expf(-(acc[j].w + bs)));
    if (o < 64) {  // r-part -> X0'^T row (2+o)*64+b, times hx
      const float* hxp = hx + ((size_t)b << 16) + (size_t)n * 64 + o;
      u16x4 s;
      s.x = f2bf(v.x * hxp[0 * 64]);
      s.y = f2bf(v.y * hxp[1 * 64]);
      s.z = f2bf(v.z * hxp[2 * 64]);
      s.w = f2bf(v.w * hxp[3 * 64]);
      *(u16x4*)&X0p[(size_t)((2 + o) * 64 + b) * NN + n] = s;
    } else {  // u-part -> uout (d_out scratch)
      float* up = uout + (((size_t)b << 10) + n) * 64 + (o - 64);
      up[0 * 64] = v.x; up[1 * 64] = v.y; up[2 * 64] = v.z; up[3 * 64] = v.w;
    }
  }
}

// gconv2 projection: tanh + GRU blend. uin aliases out (same layout) - no restrict.
__global__ __launch_bounds__(256) void proj2(
    const u16* __restrict__ X0, const u16* __restrict__ X1, const u16* __restrict__ X2,
    const u16* __restrict__ X3, const u16* __restrict__ X4,
    const u16* __restrict__ Wt, const float* __restrict__ bias,
    const float* __restrict__ hx, const float* uin, float* out) {
  __shared__ u16 A[KPAD * 66];
  const int t = threadIdx.x;
  const int n0 = blockIdx.x * 64;
  const int b = blockIdx.y;
  stage_x(A, X0, 0, b, n0, t);
  stage_x(A, X1, 1, b, n0, t);
  stage_x(A, X2, 2, b, n0, t);
  stage_x(A, X3, 3, b, n0, t);
  stage_x(A, X4, 4, b, n0, t);
  zero_pad_rows(A, t);
  __syncthreads();

  const int lane = t & 63;
  const int w = t >> 6;
  const int fr = lane & 15;
  const int ko8 = (lane >> 4) * 8;

  f32x4 acc[4];
#pragma unroll
  for (int j = 0; j < 4; j++) acc[j] = f32x4{0.f, 0.f, 0.f, 0.f};

  for (int kc = 0; kc < KPAD; kc += 32) {
    s16x8 af;
#pragma unroll
    for (int j = 0; j < 8; j++)
      af[j] = (short)A[(kc + ko8 + j) * 66 + w * 16 + fr];
#pragma unroll
    for (int j = 0; j < 4; j++) {
      s16x8 bf = *(const s16x8*)&Wt[(size_t)(j * 16 + fr) * KPAD + kc + ko8];
      acc[j] = __builtin_amdgcn_mfma_f32_16x16x32_bf16(af, bf, acc[j], 0, 0, 0);
    }
  }

  const int nl0 = (lane >> 4) * 4;
  const int n = n0 + w * 16 + nl0;  // + reg
#pragma unroll
  for (int j = 0; j < 4; j++) {
    const int o = j * 16 + fr;
    const float bs = bias[o];
    const size_t base = (((size_t)b << 10) + n) * 64 + o;  // + reg*64
    float c0 = tanhf(acc[j].x + bs);
    float c1 = tanhf(acc[j].y + bs);
    float c2 = tanhf(acc[j].z + bs);
    float c3 = tanhf(acc[j].w + bs);
    float u0 = uin[base + 0 * 64], u1 = uin[base + 1 * 64];
    float u2 = uin[base + 2 * 64], u3 = uin[base + 3 * 64];
    float h0 = hx[base + 0 * 64], h1 = hx[base + 1 * 64];
    float h2 = hx[base + 2 * 64], h3 = hx[base + 3 * 64];
    out[base + 0 * 64] = u0 * h0 + (1.f - u0) * c0;
    out[base + 1 * 64] = u1 * h1 + (1.f - u1) * c1;
    out[base + 2 * 64] = u2 * h2 + (1.f - u2) * c2;
    out[base + 3 * 64] = u3 * h3 + (1.f - u3) * c3;
  }
}

// ---------------- launch ----------------

extern "C" void kernel_launch(void* const* d_in, const int* in_sizes, int n_in,
                              void* d_out, int out_size, void* d_ws, size_t ws_size,
                              hipStream_t stream) {
  (void)in_sizes; (void)n_in; (void)out_size; (void)ws_size;
  const float* inp = (const float*)d_in[0];
  const float* hx  = (const float*)d_in[1];
  const float* s0  = (const float*)d_in[2];
  const float* s1  = (const float*)d_in[3];
  const float* Wo  = (const float*)d_in[4];
  const float* bo  = (const float*)d_in[5];
  const float* Wu  = (const float*)d_in[6];
  const float* bu  = (const float*)d_in[7];
  float* out = (float*)d_out;

  char* p = (char*)d_ws;
  u16* Sb0 = (u16*)p; p += (size_t)NN * NN * 2;
  u16* Sb1 = (u16*)p; p += (size_t)NN * NN * 2;
  const size_t xbytes = (size_t)NCOLS * NN * 2;
  u16* X0T = (u16*)p; p += xbytes;
  u16* X1T = (u16*)p; p += xbytes;
  u16* X2T = (u16*)p; p += xbytes;
  u16* X3T = (u16*)p; p += xbytes;
  u16* X4T = (u16*)p; p += xbytes;
  u16* X0P = (u16*)p; p += xbytes;
  u16* Wt1 = (u16*)p; p += (size_t)128 * KPAD * 2;
  u16* Wt2 = (u16*)p; p += (size_t)64 * KPAD * 2;
  // total ws use: 4 MB + 6*8.25 MB + ~132 KB

  pack_supports<<<dim3(1024), dim3(256), 0, stream>>>(s0, s1, Sb0, Sb1);
  pack_w<<<dim3(6, 128), dim3(64), 0, stream>>>(Wo, Wt1, 128);
  pack_w<<<dim3(6, 64), dim3(64), 0, stream>>>(Wu, Wt2, 64);
  pack_x0_inputs<<<dim3(64), dim3(256), 0, stream>>>(inp, X0T, X0P);
  pack_x0_hx<<<dim3(16, 64), dim3(256), 0, stream>>>(hx, X0T);
  // gconv1 Chebyshev: X1=S0 X0, X3=S1 X0 ; X2=2 S0 X1 - X0, X4=2 S1 X3 - X0
  cheb_gemm<<<dim3(33, 8, 2), dim3(256), 0, stream>>>(Sb0, Sb1, X0T, X0T, X1T, X3T,
                                                      (const u16*)nullptr, 0);
  cheb_gemm<<<dim3(33, 8, 2), dim3(256), 0, stream>>>(Sb0, Sb1, X1T, X3T, X2T, X4T, X0T, 1);
  proj1<<<dim3(16, 64), dim3(256), 0, stream>>>(X0T, X1T, X2T, X3T, X4T, Wt1, bo, hx, X0P, out);
  // gconv2 Chebyshev on X0' (reuse X1..X4 buffers)
  cheb_gemm<<<dim3(33, 8, 2), dim3(256), 0, stream>>>(Sb0, Sb1, X0P, X0P, X1T, X3T,
                                                      (const u16*)nullptr, 0);
  cheb_gemm<<<dim3(33, 8, 2), dim3(256), 0, stream>>>(Sb0, Sb1, X1T, X3T, X2T, X4T, X0P, 1);
  proj2<<<dim3(16, 64), dim3(256), 0, stream>>>(X0P, X1T, X2T, X3T, X4T, Wt2, bu, hx, out, out);
}